// Round 2
// baseline (737.652 us; speedup 1.0000x reference)
//
#include <hip/hip_runtime.h>
#include <hip/hip_bf16.h>

#define HID 128

typedef __attribute__((ext_vector_type(4)))  float f32x4;
typedef __attribute__((ext_vector_type(16))) float f32x16;
typedef __attribute__((ext_vector_type(8)))  short short8;

// fp32 -> bf16, round-to-nearest-even, via integer ops (no HIP bf16 types:
// __hip_bfloat162 is not trivially copyable on this ROCm so bit_cast fails).
static __device__ __forceinline__ unsigned short f2bf_u(float f) {
  unsigned u = __builtin_bit_cast(unsigned, f);
  return (unsigned short)((u + 0x7fffu + ((u >> 16) & 1u)) >> 16);
}

static __device__ __forceinline__ unsigned pk2(float a, float b) {
  return (unsigned)f2bf_u(a) | ((unsigned)f2bf_u(b) << 16);
}

static __device__ __forceinline__ short f2bf(float f) {
  return (short)f2bf_u(f);
}

static __device__ __forceinline__ short8 pack8(const f32x4 x, const f32x4 y) {
  union { unsigned u[4]; short8 s; } r;
  r.u[0] = pk2(x[0], x[1]); r.u[1] = pk2(x[2], x[3]);
  r.u[2] = pk2(y[0], y[1]); r.u[3] = pk2(y[2], y[3]);
  return r.s;
}

// Uc[g][n] = b1[n] + sum_k u[g][k] * W1[384+k][n]   (exact fp32)
__global__ void prep_uc(const float* __restrict__ u, const float* __restrict__ W1,
                        const float* __restrict__ b1, float* __restrict__ Uc) {
  __shared__ float us[HID];
  const int g = blockIdx.x, n = threadIdx.x;
  us[n] = u[g * HID + n];
  __syncthreads();
  float acc = b1[n];
  const float* w = W1 + 3 * HID * HID + n;
  #pragma unroll 8
  for (int k = 0; k < HID; ++k) acc += us[k] * w[k * HID];
  Uc[g * HID + n] = acc;
}

// Block = 4 waves; wave w owns output cols [32w, 32w+32).
// Layer-1 weights (K=384 slice) + layer-2 weights (K=128 slice) live in VGPRs.
// A-fragments stream from global (fp32 -> bf16 in regs). h goes through
// swizzled LDS to convert MFMA C-layout -> A-layout between the two GEMMs.
__global__ __launch_bounds__(256, 2) void edge_mlp(
    const float* __restrict__ src, const float* __restrict__ dst,
    const float* __restrict__ ea, const int* __restrict__ batch,
    const float* __restrict__ W1, const float* __restrict__ W2,
    const float* __restrict__ b2, const float* __restrict__ Uc,
    float* __restrict__ out, int E, int nTiles) {
  __shared__ __align__(16) short hlds[64 * HID];  // 16 KB

  const int lane = threadIdx.x & 63;
  const int wave = threadIdx.x >> 6;   // n-tile owner
  const int l31  = lane & 31;
  const int kh   = lane >> 5;          // k-half of the fragment
  const int ncol = wave * 32 + l31;

  // ---- preload weight fragments into VGPRs (bf16) ----
  short8 B1f[24];
  #pragma unroll
  for (int s = 0; s < 24; ++s) {
    const float* p = W1 + (long)(s * 16 + kh * 8) * HID + ncol;
    union { unsigned u[4]; short8 s8; } r;
    #pragma unroll
    for (int j = 0; j < 4; ++j)
      r.u[j] = pk2(p[(long)(2 * j) * HID], p[(long)(2 * j + 1) * HID]);
    B1f[s] = r.s8;
  }
  short8 B2f[8];
  #pragma unroll
  for (int s = 0; s < 8; ++s) {
    const float* p = W2 + (long)(s * 16 + kh * 8) * HID + ncol;
    union { unsigned u[4]; short8 s8; } r;
    #pragma unroll
    for (int j = 0; j < 4; ++j)
      r.u[j] = pk2(p[(long)(2 * j) * HID], p[(long)(2 * j + 1) * HID]);
    B2f[s] = r.s8;
  }
  const float b2v = b2[ncol];

  for (int t = blockIdx.x; t < nTiles; t += gridDim.x) {
    const int e0 = t * 64;
    const int rA = min(e0 + l31,      E - 1);  // slab0 edge row
    const int rB = min(e0 + 32 + l31, E - 1);  // slab1 edge row

    f32x16 acc0, acc1;
    #pragma unroll
    for (int i = 0; i < 16; ++i) { acc0[i] = 0.f; acc1[i] = 0.f; }

    // ---- layer 1: [64 x 384] @ [384 x 32] ----
    const float* const SRC3[3] = {src, dst, ea};
    #pragma unroll
    for (int c = 0; c < 3; ++c) {
      const float* pa = SRC3[c] + (long)rA * HID + kh * 8;
      const float* pb = SRC3[c] + (long)rB * HID + kh * 8;
      #pragma unroll
      for (int ss = 0; ss < 8; ++ss) {
        const f32x4 xa0 = *(const f32x4*)(pa + ss * 16);
        const f32x4 xa1 = *(const f32x4*)(pa + ss * 16 + 4);
        const f32x4 xb0 = *(const f32x4*)(pb + ss * 16);
        const f32x4 xb1 = *(const f32x4*)(pb + ss * 16 + 4);
        const short8 a0 = pack8(xa0, xa1);
        const short8 a1 = pack8(xb0, xb1);
        acc0 = __builtin_amdgcn_mfma_f32_32x32x16_bf16(a0, B1f[c * 8 + ss], acc0, 0, 0, 0);
        acc1 = __builtin_amdgcn_mfma_f32_32x32x16_bf16(a1, B1f[c * 8 + ss], acc1, 0, 0, 0);
      }
    }

    // ---- add gathered per-graph term (batch is sorted: fast uniform path) ----
    const int gA = batch[min(e0, E - 1)];
    const int gB = batch[min(e0 + 63, E - 1)];
    if (gA == gB) {
      const float ucv = Uc[(long)gA * HID + ncol];
      #pragma unroll
      for (int i = 0; i < 16; ++i) { acc0[i] += ucv; acc1[i] += ucv; }
    } else {
      #pragma unroll
      for (int i = 0; i < 16; ++i) {
        const int crow = (i & 3) + 8 * (i >> 2) + 4 * kh;
        acc0[i] += Uc[(long)batch[min(e0 + crow,      E - 1)] * HID + ncol];
        acc1[i] += Uc[(long)batch[min(e0 + 32 + crow, E - 1)] * HID + ncol];
      }
    }

    // ---- relu, cvt, stash h in LDS (C-layout write, XOR swizzle) ----
    #pragma unroll
    for (int i = 0; i < 16; ++i) {
      const int crow = (i & 3) + 8 * (i >> 2) + 4 * kh;
      const int R0 = crow, R1 = 32 + crow;
      hlds[R0 * HID + (ncol ^ ((R0 & 7) << 3))] = f2bf(fmaxf(acc0[i], 0.f));
      hlds[R1 * HID + (ncol ^ ((R1 & 7) << 3))] = f2bf(fmaxf(acc1[i], 0.f));
    }
    __syncthreads();

    // ---- layer 2: [64 x 128] @ [128 x 32] ----
    f32x16 o0, o1;
    #pragma unroll
    for (int i = 0; i < 16; ++i) { o0[i] = 0.f; o1[i] = 0.f; }
    #pragma unroll
    for (int s = 0; s < 8; ++s) {
      const int k0 = s * 16 + kh * 8;
      const int RA2 = l31, RB2 = 32 + l31;
      const short8 ha = *(const short8*)&hlds[RA2 * HID + (k0 ^ ((RA2 & 7) << 3))];
      const short8 hb = *(const short8*)&hlds[RB2 * HID + (k0 ^ ((RB2 & 7) << 3))];
      o0 = __builtin_amdgcn_mfma_f32_32x32x16_bf16(ha, B2f[s], o0, 0, 0, 0);
      o1 = __builtin_amdgcn_mfma_f32_32x32x16_bf16(hb, B2f[s], o1, 0, 0, 0);
    }

    // ---- epilogue: + b2, store fp32 ----
    #pragma unroll
    for (int i = 0; i < 16; ++i) {
      const int crow = (i & 3) + 8 * (i >> 2) + 4 * kh;
      const int eA = e0 + crow, eB = e0 + 32 + crow;
      if (eA < E) out[(long)eA * HID + ncol] = o0[i] + b2v;
      if (eB < E) out[(long)eB * HID + ncol] = o1[i] + b2v;
    }
    __syncthreads();  // protect hlds before next tile
  }
}

extern "C" void kernel_launch(void* const* d_in, const int* in_sizes, int n_in,
                              void* d_out, int out_size, void* d_ws, size_t ws_size,
                              hipStream_t stream) {
  const float* src   = (const float*)d_in[0];
  const float* dst   = (const float*)d_in[1];
  const float* ea    = (const float*)d_in[2];
  const float* u     = (const float*)d_in[3];
  const int*   batch = (const int*)d_in[4];
  const float* W1    = (const float*)d_in[5];
  const float* b1    = (const float*)d_in[6];
  const float* W2    = (const float*)d_in[7];
  const float* b2    = (const float*)d_in[8];
  float* out = (float*)d_out;
  float* Uc  = (float*)d_ws;            // G*HID fp32 = 256 KB scratch

  const int E = in_sizes[0] / HID;
  const int G = in_sizes[3] / HID;

  prep_uc<<<G, HID, 0, stream>>>(u, W1, b1, Uc);

  const int nTiles = (E + 63) / 64;
  const int grid = nTiles < 1024 ? nTiles : 1024;
  edge_mlp<<<grid, 256, 0, stream>>>(src, dst, ea, batch, W1, W2, b2, Uc, out, E, nTiles);
}